// Round 2
// baseline (215.907 us; speedup 1.0000x reference)
//
#include <hip/hip_runtime.h>
#include <hip/hip_bf16.h>

// ROM addressing head (NTM-style). B=4096, N=128 rows, M=64 key dim.
// Input dtypes are ambiguous (harness label says bf16 is present, but an
// all-bf16 read produced NaN => at least one input is f32). We detect each
// tensor's dtype at runtime (bf16 decode of f32 words yields huge/NaN values
// w.h.p.) and branch uniformly in the main kernel.

constexpr int ROM_N = 128;
constexpr int ROM_M = 64;
constexpr int N_IN  = 7;

__device__ __forceinline__ float bf2f(unsigned short u) {
    union { unsigned int i; float f; } v;
    v.i = ((unsigned int)u) << 16;
    return v.f;
}

__device__ __forceinline__ unsigned short f2bf(float f) {
    union { float f; unsigned int i; } v; v.f = f;
    unsigned int x = v.i;
    x += 0x7fffu + ((x >> 16) & 1u);   // round-to-nearest-even
    return (unsigned short)(x >> 16);
}

__device__ __forceinline__ float waveReduceSum(float v) {
#pragma unroll
    for (int off = 32; off > 0; off >>= 1) v += __shfl_down(v, off, 64);
    return v;
}

__device__ __forceinline__ float waveReduceMax(float v) {
#pragma unroll
    for (int off = 32; off > 0; off >>= 1) v = fmaxf(v, __shfl_down(v, off, 64));
    return v;
}

struct DetectArgs {
    const void* p[N_IN];
    int n[N_IN];
};

// flags[0] = bitmask, bit j set => input j is f32. flags[1] = 1 => output bf16.
__global__ void detect_kernel(DetectArgs a, int* flags) {
    const int t = threadIdx.x;
    int isf32 = 0;
    if (t < N_IN) {
        const unsigned short* u = (const unsigned short*)a.p[t];
        int c = a.n[t] < 64 ? a.n[t] : 64;
        for (int i = 0; i < c; ++i) {
            float v = bf2f(u[i]);
            if (!(fabsf(v) < 1e4f)) isf32 = 1;   // catches Inf/NaN too
        }
    }
    unsigned long long mask = __ballot(isf32 != 0);
    if (t == 0) {
        int f32mask = (int)(mask & 0x7Full);
        flags[0] = f32mask;
        flags[1] = (f32mask != 0x7F) ? 1 : 0;    // any bf16 input => bf16 out
    }
}

__device__ __forceinline__ float ld1(const void* p, size_t i, bool f32) {
    return f32 ? ((const float*)p)[i] : bf2f(((const unsigned short*)p)[i]);
}

__global__ __launch_bounds__(128) void rom_kernel(
    const void* __restrict__ memory,   // [B,N,M]
    const void* __restrict__ kvec,     // [B,M]
    const void* __restrict__ beta_in,  // [B]
    const void* __restrict__ g_in,     // [B]
    const void* __restrict__ s_in,     // [B,3]
    const void* __restrict__ gamma_in, // [B]
    const void* __restrict__ wprev,    // [B,N]
    void* __restrict__ outp,           // [B,N]
    const int* __restrict__ flags)
{
    const int b = blockIdx.x;
    const int t = threadIdx.x;
    const int wave = t >> 6;
    const int lane = t & 63;

    const int fm = flags[0];
    const bool memF32 = (fm >> 0) & 1, kF32 = (fm >> 1) & 1, beF32 = (fm >> 2) & 1;
    const bool gF32 = (fm >> 3) & 1, sF32 = (fm >> 4) & 1, gaF32 = (fm >> 5) & 1;
    const bool wpF32 = (fm >> 6) & 1;
    const bool outBf = flags[1] != 0;

    __shared__ float kk[ROM_M];
    __shared__ float scal[6];       // beta, g, s0, s1, s2, gamma
    __shared__ float keynorm;
    __shared__ float wredm[2], wreds[2], wredn[2];
    __shared__ float wgs[ROM_N];

    if (t < ROM_M) {
        float kv = ld1(kvec, (size_t)b * ROM_M + t, kF32) + 1e-16f;
        kk[t] = kv;
        float ss = waveReduceSum(kv * kv);
        if (t == 0) keynorm = fmaxf(sqrtf(ss), 1e-8f);
    }
    if (t == 64) {
        scal[0] = log1pf(expf(ld1(beta_in, b, beF32)));             // softplus
        scal[1] = 1.0f / (1.0f + expf(-ld1(g_in, b, gF32)));        // sigmoid
        float s0 = ld1(s_in, (size_t)b * 3 + 0, sF32);
        float s1 = ld1(s_in, (size_t)b * 3 + 1, sF32);
        float s2 = ld1(s_in, (size_t)b * 3 + 2, sF32);
        float mx = fmaxf(s0, fmaxf(s1, s2));
        float e0 = expf(s0 - mx), e1 = expf(s1 - mx), e2 = expf(s2 - mx);
        float inv = 1.0f / (e0 + e1 + e2);
        scal[2] = e0 * inv; scal[3] = e1 * inv; scal[4] = e2 * inv;
        scal[5] = 1.0f + log1pf(expf(ld1(gamma_in, b, gaF32)));     // 1+softplus
    }
    __syncthreads();

    // cosine similarity for row t (dot and ||row|| in one pass)
    float dot = 0.0f, ssq = 0.0f;
    const size_t rowOff = ((size_t)b * ROM_N + t) * ROM_M;
    if (memF32) {
        const float4* rv = reinterpret_cast<const float4*>((const float*)memory + rowOff);
#pragma unroll
        for (int i = 0; i < 16; ++i) {
            float4 q = rv[i];
            float a0 = q.x + 1e-16f, a1 = q.y + 1e-16f;
            float a2 = q.z + 1e-16f, a3 = q.w + 1e-16f;
            dot += a0 * kk[i*4] + a1 * kk[i*4+1] + a2 * kk[i*4+2] + a3 * kk[i*4+3];
            ssq += a0 * a0 + a1 * a1 + a2 * a2 + a3 * a3;
        }
    } else {
        const uint4* rv = reinterpret_cast<const uint4*>((const unsigned short*)memory + rowOff);
#pragma unroll
        for (int i = 0; i < 8; ++i) {
            uint4 p = rv[i];
            unsigned int wds[4] = {p.x, p.y, p.z, p.w};
#pragma unroll
            for (int j = 0; j < 4; ++j) {
                float lo = bf2f((unsigned short)(wds[j] & 0xffffu)) + 1e-16f;
                float hi = bf2f((unsigned short)(wds[j] >> 16)) + 1e-16f;
                int m0 = i * 8 + j * 2;
                dot += lo * kk[m0] + hi * kk[m0 + 1];
                ssq += lo * lo + hi * hi;
            }
        }
    }
    float mem_norm = fmaxf(sqrtf(ssq), 1e-8f);
    float x = scal[0] * (dot / (mem_norm * keynorm));   // beta * cos

    // block softmax over 128 rows
    float m = waveReduceMax(x);
    if (lane == 0) wredm[wave] = m;
    __syncthreads();
    float gmax = fmaxf(wredm[0], wredm[1]);
    float e = expf(x - gmax);
    float ps = waveReduceSum(e);
    if (lane == 0) wreds[wave] = ps;
    __syncthreads();
    float wc = e / (wreds[0] + wreds[1]);

    // interpolate
    float g = scal[1];
    float wp = ld1(wprev, (size_t)b * ROM_N + t, wpF32);
    float wg = g * wc + (1.0f - g) * wp;
    wgs[t] = wg;
    __syncthreads();

    // circular 3-tap shift
    float wh = wgs[(t + ROM_N - 1) & (ROM_N - 1)] * scal[2]
             + wg * scal[3]
             + wgs[(t + 1) & (ROM_N - 1)] * scal[4];

    // sharpen + normalize
    float w = powf(wh, scal[5]);
    float pn = waveReduceSum(w);
    if (lane == 0) wredn[wave] = pn;
    __syncthreads();
    float total = wredn[0] + wredn[1] + 1e-16f;
    float val = w / total;

    const size_t oi = (size_t)b * ROM_N + t;
    if (outBf) ((unsigned short*)outp)[oi] = f2bf(val);
    else       ((float*)outp)[oi] = val;
}

extern "C" void kernel_launch(void* const* d_in, const int* in_sizes, int n_in,
                              void* d_out, int out_size, void* d_ws, size_t ws_size,
                              hipStream_t stream) {
    DetectArgs da;
    for (int i = 0; i < N_IN; ++i) { da.p[i] = d_in[i]; da.n[i] = in_sizes[i]; }
    int* flags = (int*)d_ws;

    detect_kernel<<<1, 64, 0, stream>>>(da, flags);

    const int B = in_sizes[0] / (ROM_N * ROM_M);
    rom_kernel<<<B, ROM_N, 0, stream>>>(d_in[0], d_in[1], d_in[2], d_in[3],
                                        d_in[4], d_in[5], d_in[6], d_out, flags);
}

// Round 3
// 207.777 us; speedup vs baseline: 1.0391x; 1.0391x over previous
//
#include <hip/hip_runtime.h>
#include <hip/hip_bf16.h>

// ROM addressing head (NTM-style). B=4096, N=128 rows, M=64 key dim.
// Mixed/unknown input dtypes -> per-block runtime detection (f32 words decoded
// as bf16 give |v|>=1e4 or non-finite w.h.p.; genuine inputs here are O(1)).
// Lane-contiguous global loads: thread t loads flat 16B(f32)/8B(bf16) chunk
// t+128*i covering 4 elements of row r=t/16+8i; partials reduced via LDS.

constexpr int ROM_N = 128;
constexpr int ROM_M = 64;
constexpr int N_IN  = 7;
constexpr int PSTR  = 36;   // floats per partial row: 32 used + 4 pad (16B-aligned, bank spread)

__device__ __forceinline__ float bf2f(unsigned short u) {
    union { unsigned int i; float f; } v;
    v.i = ((unsigned int)u) << 16;
    return v.f;
}

__device__ __forceinline__ unsigned short f2bf(float f) {
    union { float f; unsigned int i; } v; v.f = f;
    unsigned int x = v.i;
    x += 0x7fffu + ((x >> 16) & 1u);   // round-to-nearest-even
    return (unsigned short)(x >> 16);
}

__device__ __forceinline__ float waveReduceSum(float v) {
#pragma unroll
    for (int off = 32; off > 0; off >>= 1) v += __shfl_down(v, off, 64);
    return v;
}

__device__ __forceinline__ float waveReduceMax(float v) {
#pragma unroll
    for (int off = 32; off > 0; off >>= 1) v = fmaxf(v, __shfl_down(v, off, 64));
    return v;
}

struct KArgs { const void* p[N_IN]; };

__device__ __forceinline__ float ld1(const void* p, size_t i, bool f32) {
    return f32 ? ((const float*)p)[i] : bf2f(((const unsigned short*)p)[i]);
}

__global__ __launch_bounds__(128) void rom_kernel(KArgs a, void* __restrict__ outp) {
    const int b = blockIdx.x;
    const int t = threadIdx.x;
    const int wave = t >> 6;
    const int lane = t & 63;
    const int g16 = t & 15;    // column block within row (4 elems)
    const int a16 = t >> 4;    // row-group base (0..7)

    __shared__ int   sf[N_IN];
    __shared__ float kk[ROM_M];
    __shared__ float scal[6];        // beta, g, s0, s1, s2, gamma
    __shared__ float keynorm;
    __shared__ float wredm[2], wreds[2], wredn[2];
    __shared__ float wgs[ROM_N];
    __shared__ float part[ROM_N * PSTR];   // [r][g][{dot,ssq}] padded

    // --- per-block dtype detection (reads are L2/L3 hits after block 0) ---
    if (t < N_IN) {
        const unsigned short* u = (const unsigned short*)a.p[t];
        int bad = 0;
#pragma unroll
        for (int i = 0; i < 64; ++i) {
            float v = bf2f(u[i]);
            if (!(fabsf(v) < 1e4f)) bad = 1;   // catches Inf/NaN too
        }
        sf[t] = bad;                            // 1 => tensor is f32
    }
    __syncthreads();
    int fm = 0;
#pragma unroll
    for (int j = 0; j < N_IN; ++j) fm |= sf[j] << j;
    const bool memF32 = (fm >> 0) & 1, kF32 = (fm >> 1) & 1, beF32 = (fm >> 2) & 1;
    const bool gF32 = (fm >> 3) & 1, sF32 = (fm >> 4) & 1, gaF32 = (fm >> 5) & 1;
    const bool wpF32 = (fm >> 6) & 1;
    const bool outBf = (fm != 0x7F);            // any bf16 input => bf16 out

    // --- stage key (f32, +1e-16) and squashed params ---
    if (t < ROM_M) {
        float kv = ld1(a.p[1], (size_t)b * ROM_M + t, kF32) + 1e-16f;
        kk[t] = kv;
        float ss = waveReduceSum(kv * kv);
        if (t == 0) keynorm = fmaxf(sqrtf(ss), 1e-8f);
    }
    if (t == 64) {
        scal[0] = log1pf(expf(ld1(a.p[2], b, beF32)));            // softplus(beta)
        scal[1] = 1.0f / (1.0f + expf(-ld1(a.p[3], b, gF32)));    // sigmoid(g)
        float s0 = ld1(a.p[4], (size_t)b * 3 + 0, sF32);
        float s1 = ld1(a.p[4], (size_t)b * 3 + 1, sF32);
        float s2 = ld1(a.p[4], (size_t)b * 3 + 2, sF32);
        float mx = fmaxf(s0, fmaxf(s1, s2));
        float e0 = expf(s0 - mx), e1 = expf(s1 - mx), e2 = expf(s2 - mx);
        float inv = 1.0f / (e0 + e1 + e2);
        scal[2] = e0 * inv; scal[3] = e1 * inv; scal[4] = e2 * inv;
        scal[5] = 1.0f + log1pf(expf(ld1(a.p[5], b, gaF32)));     // 1+softplus(gamma)
    }
    __syncthreads();

    // --- lane-contiguous memory loads; per-chunk partial dot/ssq -> LDS ---
    const float4 kcv = ((const float4*)kk)[g16];   // this thread's 4 key values
    if (memF32) {
        const float4* mv = (const float4*)((const float*)a.p[0] + (size_t)b * (ROM_N * ROM_M));
#pragma unroll
        for (int i = 0; i < 16; ++i) {
            float4 v = mv[t + 128 * i];
            float a0 = v.x + 1e-16f, a1 = v.y + 1e-16f;
            float a2 = v.z + 1e-16f, a3 = v.w + 1e-16f;
            float d = a0 * kcv.x + a1 * kcv.y + a2 * kcv.z + a3 * kcv.w;
            float s = a0 * a0 + a1 * a1 + a2 * a2 + a3 * a3;
            int r = a16 + 8 * i;
            ((float2*)part)[r * (PSTR / 2) + g16] = make_float2(d, s);
        }
    } else {
        const uint2* mv = (const uint2*)((const unsigned short*)a.p[0] + (size_t)b * (ROM_N * ROM_M));
#pragma unroll
        for (int i = 0; i < 16; ++i) {
            uint2 u = mv[t + 128 * i];
            float a0 = bf2f((unsigned short)(u.x & 0xffffu)) + 1e-16f;
            float a1 = bf2f((unsigned short)(u.x >> 16)) + 1e-16f;
            float a2 = bf2f((unsigned short)(u.y & 0xffffu)) + 1e-16f;
            float a3 = bf2f((unsigned short)(u.y >> 16)) + 1e-16f;
            float d = a0 * kcv.x + a1 * kcv.y + a2 * kcv.z + a3 * kcv.w;
            float s = a0 * a0 + a1 * a1 + a2 * a2 + a3 * a3;
            int r = a16 + 8 * i;
            ((float2*)part)[r * (PSTR / 2) + g16] = make_float2(d, s);
        }
    }
    __syncthreads();

    // --- row t reduction: 8x ds_read_b128 over this row's 16 partials ---
    float dot = 0.0f, ssq = 0.0f;
    const float4* pr = (const float4*)(part + t * PSTR);
#pragma unroll
    for (int j = 0; j < 8; ++j) {
        float4 v = pr[j];
        dot += v.x + v.z;
        ssq += v.y + v.w;
    }
    float mem_norm = fmaxf(sqrtf(ssq), 1e-8f);
    float x = scal[0] * (dot / (mem_norm * keynorm));   // beta * cosine

    // --- block softmax over 128 rows ---
    float m = waveReduceMax(x);
    if (lane == 0) wredm[wave] = m;
    __syncthreads();
    float gmax = fmaxf(wredm[0], wredm[1]);
    float e = expf(x - gmax);
    float ps = waveReduceSum(e);
    if (lane == 0) wreds[wave] = ps;
    __syncthreads();
    float wc = e / (wreds[0] + wreds[1]);

    // --- interpolate with previous weighting ---
    float g = scal[1];
    float wp = ld1(a.p[6], (size_t)b * ROM_N + t, wpF32);
    float wg = g * wc + (1.0f - g) * wp;
    wgs[t] = wg;
    __syncthreads();

    // --- circular 3-tap shift ---
    float wh = wgs[(t + ROM_N - 1) & (ROM_N - 1)] * scal[2]
             + wg * scal[3]
             + wgs[(t + 1) & (ROM_N - 1)] * scal[4];

    // --- sharpen + normalize ---
    float w = powf(wh, scal[5]);
    float pn = waveReduceSum(w);
    if (lane == 0) wredn[wave] = pn;
    __syncthreads();
    float total = wredn[0] + wredn[1] + 1e-16f;
    float val = w / total;

    const size_t oi = (size_t)b * ROM_N + t;
    if (outBf) ((unsigned short*)outp)[oi] = f2bf(val);
    else       ((float*)outp)[oi] = val;
}

extern "C" void kernel_launch(void* const* d_in, const int* in_sizes, int n_in,
                              void* d_out, int out_size, void* d_ws, size_t ws_size,
                              hipStream_t stream) {
    KArgs a;
    for (int i = 0; i < N_IN; ++i) a.p[i] = d_in[i];
    const int B = in_sizes[0] / (ROM_N * ROM_M);
    rom_kernel<<<B, ROM_N, 0, stream>>>(a, d_out);
}

// Round 5
// 194.975 us; speedup vs baseline: 1.1074x; 1.0657x over previous
//
#include <hip/hip_runtime.h>
#include <hip/hip_bf16.h>

// ROM addressing head (NTM-style). B=4096, N=128 rows, M=64 key dim.
// 2 batches per 256-thread block (halves dispatch count; ~12KB LDS ->
// 32 waves/CU, all 2048 blocks co-resident). Runtime per-tensor dtype
// detection via 2-wave ballot scan (f32 words decoded as bf16 give
// |v|>=1e4 / non-finite w.h.p.; proven on this dataset in R2/R3).
// No softmax max-pass: |x| <= softplus(beta) ~ 5, exp is f32-safe.
// Nontemporal loads need native ext_vector types (HIP_vector_type is a
// class -> builtin rejects it; R4 compile failure).

constexpr int ROM_N = 128;
constexpr int ROM_M = 64;
constexpr int N_IN  = 7;
constexpr int PROW2 = 5;    // float2 per partial row: 4 used + 1 pad

typedef float  fx4 __attribute__((ext_vector_type(4)));
typedef unsigned int ux2 __attribute__((ext_vector_type(2)));

__device__ __forceinline__ float bf2f(unsigned short u) {
    union { unsigned int i; float f; } v;
    v.i = ((unsigned int)u) << 16;
    return v.f;
}

__device__ __forceinline__ unsigned short f2bf(float f) {
    union { float f; unsigned int i; } v; v.f = f;
    unsigned int x = v.i;
    x += 0x7fffu + ((x >> 16) & 1u);   // round-to-nearest-even
    return (unsigned short)(x >> 16);
}

__device__ __forceinline__ float waveReduceSum(float v) {
#pragma unroll
    for (int off = 32; off > 0; off >>= 1) v += __shfl_down(v, off, 64);
    return v;
}

struct KArgs { const void* p[N_IN]; };

__device__ __forceinline__ float ld1(const void* p, size_t i, bool f32) {
    return f32 ? ((const float*)p)[i] : bf2f(((const unsigned short*)p)[i]);
}

__global__ __launch_bounds__(256) void rom_kernel(KArgs a, void* __restrict__ outp) {
    const int t    = threadIdx.x;
    const int h    = t >> 7;          // local batch half (0/1)
    const int tt   = t & 127;         // thread within half
    const int b    = blockIdx.x * 2 + h;
    const int w    = t >> 6;          // wave id 0..3
    const int wv   = w & 1;           // wave within half
    const int lane = t & 63;
    const int g16  = tt & 15;         // column chunk (4 elems)
    const int a16  = tt >> 4;         // row-group base 0..7

    __shared__ int    sf[2];
    __shared__ float  kk[2][ROM_M];
    __shared__ float  scal[2][6];      // beta, g, s0, s1, s2, gamma
    __shared__ float  keynorm[2];
    __shared__ float  wreds[2][2], wredn[2][2];
    __shared__ float  wgs[2][ROM_N];
    __shared__ float2 part[2][ROM_N * PROW2];

    // --- dtype detection: waves 0/1, 16 lanes x 4 elems per tensor, ballot ---
    {
        int bad = 0;
        if (w < 2) {
            int j = t >> 4;                       // tensor id 0..7
            if (j < N_IN) {
                ux2 q = ((const ux2*)a.p[j])[t & 15];   // 4 bf16 halfwords
                unsigned int hw[4] = {q.x & 0xffffu, q.x >> 16,
                                      q.y & 0xffffu, q.y >> 16};
#pragma unroll
                for (int e = 0; e < 4; ++e) {
                    float v = bf2f((unsigned short)hw[e]);
                    if (!(fabsf(v) < 1e4f)) bad = 1;   // catches Inf/NaN too
                }
            }
        }
        unsigned long long mb = __ballot(bad);
        if (lane == 0 && w < 2) {
            int f = 0;
#pragma unroll
            for (int j4 = 0; j4 < 4; ++j4)
                if ((mb >> (16 * j4)) & 0xFFFFull) f |= 1 << (w * 4 + j4);
            sf[w] = f;
        }
    }
    __syncthreads();
    const int fm = sf[0] | sf[1];               // bit j set => input j is f32
    const bool memF32 = (fm >> 0) & 1, kF32 = (fm >> 1) & 1, beF32 = (fm >> 2) & 1;
    const bool gF32 = (fm >> 3) & 1, sF32 = (fm >> 4) & 1, gaF32 = (fm >> 5) & 1;
    const bool wpF32 = (fm >> 6) & 1;
    const bool outBf = (fm != 0x7F);

    // --- per-half: stage key (waves 0/2), squash params (tt==64) ---
    if (tt < 64) {
        float kv = ld1(a.p[1], (size_t)b * ROM_M + tt, kF32) + 1e-16f;
        kk[h][tt] = kv;
        float ss = waveReduceSum(kv * kv);
        if (lane == 0) keynorm[h] = fmaxf(sqrtf(ss), 1e-8f);
    }
    if (tt == 64) {
        scal[h][0] = log1pf(expf(ld1(a.p[2], b, beF32)));           // softplus(beta)
        scal[h][1] = 1.0f / (1.0f + expf(-ld1(a.p[3], b, gF32)));   // sigmoid(g)
        float s0 = ld1(a.p[4], (size_t)b * 3 + 0, sF32);
        float s1 = ld1(a.p[4], (size_t)b * 3 + 1, sF32);
        float s2 = ld1(a.p[4], (size_t)b * 3 + 2, sF32);
        float mx = fmaxf(s0, fmaxf(s1, s2));
        float e0 = expf(s0 - mx), e1 = expf(s1 - mx), e2 = expf(s2 - mx);
        float inv = 1.0f / (e0 + e1 + e2);
        scal[h][2] = e0 * inv; scal[h][3] = e1 * inv; scal[h][4] = e2 * inv;
        scal[h][5] = 1.0f + log1pf(expf(ld1(a.p[5], b, gaF32)));    // 1+softplus
    }
    // early issue: previous weighting for this row (used post-softmax)
    float wp = ld1(a.p[6], (size_t)b * ROM_N + tt, wpF32);
    __syncthreads();

    // --- lane-contiguous streaming loads; shuffle pre-reduce; LDS partials ---
    const float4 kcv = ((const float4*)kk[h])[g16];
    float2* pp = part[h];
    const size_t mbase = (size_t)b * (ROM_N * ROM_M);
    if (memF32) {
        const fx4* mv = (const fx4*)((const float*)a.p[0] + mbase);
#pragma unroll
        for (int i = 0; i < 16; ++i) {
            fx4 v = __builtin_nontemporal_load(&mv[tt + 128 * i]);
            float a0 = v.x + 1e-16f, a1 = v.y + 1e-16f;
            float a2 = v.z + 1e-16f, a3 = v.w + 1e-16f;
            float d = a0 * kcv.x + a1 * kcv.y + a2 * kcv.z + a3 * kcv.w;
            float s = a0 * a0 + a1 * a1 + a2 * a2 + a3 * a3;
            d += __shfl_xor(d, 1); s += __shfl_xor(s, 1);
            d += __shfl_xor(d, 2); s += __shfl_xor(s, 2);
            if ((g16 & 3) == 0)
                pp[(a16 + 8 * i) * PROW2 + (g16 >> 2)] = make_float2(d, s);
        }
    } else {
        const ux2* mv = (const ux2*)((const unsigned short*)a.p[0] + mbase);
#pragma unroll
        for (int i = 0; i < 16; ++i) {
            ux2 u = __builtin_nontemporal_load(&mv[tt + 128 * i]);
            float a0 = bf2f((unsigned short)(u.x & 0xffffu)) + 1e-16f;
            float a1 = bf2f((unsigned short)(u.x >> 16)) + 1e-16f;
            float a2 = bf2f((unsigned short)(u.y & 0xffffu)) + 1e-16f;
            float a3 = bf2f((unsigned short)(u.y >> 16)) + 1e-16f;
            float d = a0 * kcv.x + a1 * kcv.y + a2 * kcv.z + a3 * kcv.w;
            float s = a0 * a0 + a1 * a1 + a2 * a2 + a3 * a3;
            d += __shfl_xor(d, 1); s += __shfl_xor(s, 1);
            d += __shfl_xor(d, 2); s += __shfl_xor(s, 2);
            if ((g16 & 3) == 0)
                pp[(a16 + 8 * i) * PROW2 + (g16 >> 2)] = make_float2(d, s);
        }
    }
    __syncthreads();

    // --- row tt: reduce its 4 partials ---
    float dot = 0.0f, ssq = 0.0f;
    const float2* pr = pp + tt * PROW2;
#pragma unroll
    for (int j = 0; j < 4; ++j) { float2 v = pr[j]; dot += v.x; ssq += v.y; }
    float mem_norm = fmaxf(sqrtf(ssq), 1e-8f);
    float x = scal[h][0] * (dot / (mem_norm * keynorm[h]));   // beta * cosine

    // --- softmax over 128 rows (no max-pass: |x| <= beta ~ 5, f32-safe) ---
    float e = __expf(x);
    float ps = waveReduceSum(e);
    if (lane == 0) wreds[h][wv] = ps;
    __syncthreads();
    float wc = e / (wreds[h][0] + wreds[h][1]);

    // --- interpolate; stage for circular shift ---
    float g = scal[h][1];
    float wg = g * wc + (1.0f - g) * wp;
    wgs[h][tt] = wg;
    __syncthreads();

    // --- circular 3-tap shift ---
    float wh = wgs[h][(tt + ROM_N - 1) & (ROM_N - 1)] * scal[h][2]
             + wg * scal[h][3]
             + wgs[h][(tt + 1) & (ROM_N - 1)] * scal[h][4];

    // --- sharpen (pow via fast exp/log; wh > 0) + normalize ---
    float w2 = __expf(scal[h][5] * __logf(wh));
    float pn = waveReduceSum(w2);
    if (lane == 0) wredn[h][wv] = pn;
    __syncthreads();
    float val = w2 / (wredn[h][0] + wredn[h][1] + 1e-16f);

    const size_t oi = (size_t)b * ROM_N + tt;
    if (outBf) ((unsigned short*)outp)[oi] = f2bf(val);
    else       ((float*)outp)[oi] = val;
}

extern "C" void kernel_launch(void* const* d_in, const int* in_sizes, int n_in,
                              void* d_out, int out_size, void* d_ws, size_t ws_size,
                              hipStream_t stream) {
    KArgs a;
    for (int i = 0; i < N_IN; ++i) a.p[i] = d_in[i];
    const int B = in_sizes[0] / (ROM_N * ROM_M);
    rom_kernel<<<B / 2, 256, 0, stream>>>(a, d_out);
}